// Round 5
// baseline (299.773 us; speedup 1.0000x reference)
//
#include <hip/hip_runtime.h>
#include <hip/hip_bf16.h>
#include <stdint.h>

typedef __attribute__((ext_vector_type(8))) __bf16 bf16x8;
typedef __attribute__((ext_vector_type(16))) float f32x16;

#define GLOAD(g, l) __builtin_amdgcn_global_load_lds(                      \
    (const __attribute__((address_space(1))) void*)(g),                    \
    (__attribute__((address_space(3))) void*)(l), 16, 0, 0)

#define MFMA32 __builtin_amdgcn_mfma_f32_32x32x16_bf16

__device__ __forceinline__ unsigned short f2bf(float f) {
  unsigned u = __float_as_uint(f);
  u = (u + 0x7FFFu + ((u >> 16) & 1u)) >> 16;
  return (unsigned short)u;
}

// ---- W -> sign(W) as bf16 bits, plus per-block partial sums of |W| ------
__global__ __launch_bounds__(256) void wsign_kernel(
    const float* __restrict__ W, unsigned short* __restrict__ S,
    float* __restrict__ partials) {
  const int tid = threadIdx.x;
  const int stride = gridDim.x * 256;
  const int total4 = (4096 * 4096) / 4;
  float s = 0.f;
  for (int i = blockIdx.x * 256 + tid; i < total4; i += stride) {
    float4 w = reinterpret_cast<const float4*>(W)[i];
    ushort4 o;
    o.x = w.x > 0.f ? 0x3F80 : (w.x < 0.f ? 0xBF80 : 0);
    o.y = w.y > 0.f ? 0x3F80 : (w.y < 0.f ? 0xBF80 : 0);
    o.z = w.z > 0.f ? 0x3F80 : (w.z < 0.f ? 0xBF80 : 0);
    o.w = w.w > 0.f ? 0x3F80 : (w.w < 0.f ? 0xBF80 : 0);
    reinterpret_cast<ushort4*>(S)[i] = o;
    s += fabsf(w.x) + fabsf(w.y) + fabsf(w.z) + fabsf(w.w);
  }
#pragma unroll
  for (int off = 32; off > 0; off >>= 1) s += __shfl_down(s, off, 64);
  __shared__ float sm[4];
  if ((tid & 63) == 0) sm[tid >> 6] = s;
  __syncthreads();
  if (tid == 0) partials[blockIdx.x] = sm[0] + sm[1] + sm[2] + sm[3];
}

// ---- x f32 -> bf16 ------------------------------------------------------
__global__ __launch_bounds__(256) void xconv_kernel(
    const float* __restrict__ X, unsigned short* __restrict__ XB) {
  const int total4 = (8192 * 4096) / 4;
  const int stride = gridDim.x * 256;
  for (int i = blockIdx.x * 256 + threadIdx.x; i < total4; i += stride) {
    float4 v = reinterpret_cast<const float4*>(X)[i];
    ushort4 o;
    o.x = f2bf(v.x);
    o.y = f2bf(v.y);
    o.z = f2bf(v.z);
    o.w = f2bf(v.w);
    reinterpret_cast<ushort4*>(XB)[i] = o;
  }
}

// ---- deterministic reduce of partials -> scale = mean(|W|) --------------
__global__ __launch_bounds__(256) void finalize_kernel(
    const float* __restrict__ partials, float* __restrict__ scale) {
  const int tid = threadIdx.x;
  float s = 0.f;
  for (int i = tid; i < 2048; i += 256) s += partials[i];
#pragma unroll
  for (int off = 32; off > 0; off >>= 1) s += __shfl_down(s, off, 64);
  __shared__ float sm[4];
  if ((tid & 63) == 0) sm[tid >> 6] = s;
  __syncthreads();
  if (tid == 0) scale[0] = (sm[0] + sm[1] + sm[2] + sm[3]) * (1.0f / 16777216.0f);
}

// ---- 256x256x64 8-wave 4-phase bf16 GEMM (32x32x16 MFMA) ----------------
// Per phase: {reads; stage; [waits]; barrier; lgkm(0); setprio+8 MFMA; barrier}
// Stages: B0(t+2)@P1, B1(t+2)@P2, A0/A1(t+2)@tile-end. vmcnt(4)@P3 gates
// tile t+1's 8 loads (FIFO: B0,B1,A0,A1 per tile); vmcnt(0) at t>=NT-2.
// LDS slots (16 KiB): A[par][half] = par*2+half; B[par][half] = 4+par*2+half
__global__ __launch_bounds__(512, 2) void gemm_sign_kernel(
    const unsigned short* __restrict__ A,  // [8192][4096] bf16 bits
    const unsigned short* __restrict__ B,  // [4096][4096] bf16 sign
    const float* __restrict__ scale_p, float* __restrict__ C) {
  constexpr int M = 8192, N = 4096, K = 4096;
  constexpr int NT = K / 64;  // 64 K-tiles
  __shared__ __align__(16) unsigned short lds[65536];  // 128 KiB

  const int tid = threadIdx.x;
  const int wid = tid >> 6;
  const int lane = tid & 63;
  const int wr = wid >> 2;           // 0..1 : A half (M-rows)
  const int wc = wid & 3;            // 0..3 : 64-col group (B-rows)
  const int bh = wc >> 1;            // B half slot
  const int bsub = (wc & 1) * 4096;  // 64-row band within B half
  const int r31 = lane & 31;
  const int kq = lane >> 5;          // k-octet select
  const int L7 = lane & 7;
  // swizzled 16B-slot offsets (elements) for kkk = 0..3
  int sk[4];
#pragma unroll
  for (int k = 0; k < 4; ++k) sk[k] = ((2 * k + kq) ^ L7) * 8;

  // XCD-aware swizzle; nwg = 512, divisible by 8
  const int bid = blockIdx.x;
  const int swz = (bid & 7) * 64 + (bid >> 3);
  const int tm = swz >> 4, tn = swz & 15;

  // --- staging source addresses (per-thread, pre-inverse-swizzled) ---
  const int srow = tid >> 3;              // 0..63
  const int sg = (tid & 7) ^ (srow & 7);  // inverse-swizzled col-group
  const unsigned short* aSrc0 = A + (size_t)(tm * 256 + srow) * K + sg * 8;
  const unsigned short* aSrc1 = aSrc0 + (size_t)128 * K;
  const unsigned short* bSrc0 = B + (size_t)(tn * 256 + srow) * K + sg * 8;
  const unsigned short* bSrc1 = bSrc0 + (size_t)128 * K;

#define STAGE(srcBase, slotIdx, koff)                              \
  do {                                                             \
    const unsigned short* _s = (srcBase) + (koff);                 \
    unsigned short* _d = &lds[(slotIdx) * 8192 + wid * 512];       \
    GLOAD(_s, _d);                                                 \
    GLOAD(_s + (size_t)64 * K, _d + 4096);                         \
  } while (0)

  f32x16 acc[4][2];
#pragma unroll
  for (int mb = 0; mb < 4; ++mb)
#pragma unroll
    for (int nb = 0; nb < 2; ++nb)
#pragma unroll
      for (int r = 0; r < 16; ++r) acc[mb][nb][r] = 0.f;

  // fragment read base pointers per parity
  const unsigned short* aP0 = lds + wr * 8192 + r31 * 64;
  const unsigned short* bP0 = lds + (4 + bh) * 8192 + bsub + r31 * 64;

  // Prologue: tiles 0 and 1, FIFO order [B0 B1 A0 A1] per tile
  STAGE(bSrc0, 4, 0);
  STAGE(bSrc1, 5, 0);
  STAGE(aSrc0, 0, 0);
  STAGE(aSrc1, 1, 0);
  STAGE(bSrc0, 6, 64);
  STAGE(bSrc1, 7, 64);
  STAGE(aSrc0, 2, 64);
  STAGE(aSrc1, 3, 64);
  asm volatile("s_waitcnt vmcnt(8)" ::: "memory");  // tile 0 resident
  __builtin_amdgcn_s_barrier();

#define PH_MFMA(mb)                                                      \
  do {                                                                   \
    __builtin_amdgcn_s_setprio(1);                                       \
    _Pragma("unroll") for (int kkk = 0; kkk < 4; ++kkk)                  \
        _Pragma("unroll") for (int nb = 0; nb < 2; ++nb)                 \
            acc[mb][nb] =                                                \
        MFMA32(av[kkk], bq[nb][kkk], acc[mb][nb], 0, 0, 0);              \
    __builtin_amdgcn_s_setprio(0);                                       \
  } while (0)

  for (int t = 0; t < NT; ++t) {
    const int par = t & 1;
    const int k2 = (t + 2) * 64;
    const unsigned short* aS = aP0 + par * 16384;
    const unsigned short* bS = bP0 + par * 16384;

    // ---- P0: read all B (8) + A mb=0 (4) ----
    bf16x8 bq[2][4], av[4];
#pragma unroll
    for (int nb = 0; nb < 2; ++nb)
#pragma unroll
      for (int k = 0; k < 4; ++k)
        bq[nb][k] = *(const bf16x8*)(bS + nb * 2048 + sk[k]);
#pragma unroll
    for (int k = 0; k < 4; ++k) av[k] = *(const bf16x8*)(aS + sk[k]);
    asm volatile("s_waitcnt lgkmcnt(8)");
    __builtin_amdgcn_s_barrier();
    asm volatile("s_waitcnt lgkmcnt(0)");
    PH_MFMA(0);
    __builtin_amdgcn_s_barrier();

    // ---- P1: A mb=1; stage B0(t+2) (B[par] reads done at P0 barrier) ----
#pragma unroll
    for (int k = 0; k < 4; ++k)
      av[k] = *(const bf16x8*)(aS + 2048 + sk[k]);
    if (t + 2 < NT) STAGE(bSrc0, 4 + par * 2, k2);
    __builtin_amdgcn_s_barrier();
    asm volatile("s_waitcnt lgkmcnt(0)");
    PH_MFMA(1);
    __builtin_amdgcn_s_barrier();

    // ---- P2: A mb=2; stage B1(t+2) ----
#pragma unroll
    for (int k = 0; k < 4; ++k)
      av[k] = *(const bf16x8*)(aS + 4096 + sk[k]);
    if (t + 2 < NT) STAGE(bSrc1, 4 + par * 2 + 1, k2);
    __builtin_amdgcn_s_barrier();
    asm volatile("s_waitcnt lgkmcnt(0)");
    PH_MFMA(2);
    __builtin_amdgcn_s_barrier();

    // ---- P3: A mb=3; vmcnt gate for tile t+1's data ----
#pragma unroll
    for (int k = 0; k < 4; ++k)
      av[k] = *(const bf16x8*)(aS + 6144 + sk[k]);
    if (t >= NT - 2) {
      asm volatile("s_waitcnt vmcnt(0)" ::: "memory");
    } else {
      asm volatile("s_waitcnt vmcnt(4)" ::: "memory");
    }
    __builtin_amdgcn_s_barrier();
    asm volatile("s_waitcnt lgkmcnt(0)");
    PH_MFMA(3);
    __builtin_amdgcn_s_barrier();

    // ---- tile end: stage A0/A1(t+2) (all A[par] reads done at P3 bar) ----
    if (t + 2 < NT) {
      STAGE(aSrc0, par * 2, k2);
      STAGE(aSrc1, par * 2 + 1, k2);
    }
  }

  // ---- epilogue: C/D layout col=lane&31, row=(r&3)+8*(r>>2)+4*kq ----
  const float sc = *scale_p;
  const int erow = tm * 256 + wr * 128 + 4 * kq;
  const int ecol = tn * 256 + wc * 64 + r31;
#pragma unroll
  for (int mb = 0; mb < 4; ++mb) {
#pragma unroll
    for (int nb = 0; nb < 2; ++nb) {
      f32x16 v = acc[mb][nb];
#pragma unroll
      for (int r = 0; r < 16; ++r) {
        const int row = erow + mb * 32 + (r & 3) + 8 * (r >> 2);
        C[(size_t)row * N + ecol + nb * 32] = v[r] * sc;
      }
    }
  }
#undef STAGE
#undef PH_MFMA
}

extern "C" void kernel_launch(void* const* d_in, const int* in_sizes, int n_in,
                              void* d_out, int out_size, void* d_ws,
                              size_t ws_size, hipStream_t stream) {
  const float* x = (const float*)d_in[0];   // [8192][4096] f32
  const float* w = (const float*)d_in[1];   // [4096][4096] f32
  float* out = (float*)d_out;               // [8192][4096] f32

  char* ws = (char*)d_ws;
  unsigned short* xb = (unsigned short*)ws;                   // 64 MiB
  unsigned short* sb = (unsigned short*)(ws + 67108864);      // 32 MiB
  float* partials = (float*)(ws + 100663296);                 // 2048 f32
  float* scale = (float*)(ws + 100663296 + 8192);             // 1 f32

  wsign_kernel<<<2048, 256, 0, stream>>>(w, sb, partials);
  xconv_kernel<<<2048, 256, 0, stream>>>(x, xb);
  finalize_kernel<<<1, 256, 0, stream>>>(partials, scale);
  gemm_sign_kernel<<<512, 512, 0, stream>>>(xb, sb, scale, out);
}

// Round 6
// 264.493 us; speedup vs baseline: 1.1334x; 1.1334x over previous
//
#include <hip/hip_runtime.h>
#include <hip/hip_bf16.h>
#include <stdint.h>

typedef __attribute__((ext_vector_type(8))) __bf16 bf16x8;
typedef __attribute__((ext_vector_type(4))) float f32x4;

#define GLOAD(g, l) __builtin_amdgcn_global_load_lds(                      \
    (const __attribute__((address_space(1))) void*)(g),                    \
    (__attribute__((address_space(3))) void*)(l), 16, 0, 0)

#define MFMA __builtin_amdgcn_mfma_f32_16x16x32_bf16
#define BARRIER __builtin_amdgcn_s_barrier
#define LGKM0 asm volatile("s_waitcnt lgkmcnt(0)" ::: "memory")
#define LGKM8 asm volatile("s_waitcnt lgkmcnt(8)" ::: "memory")

__device__ __forceinline__ unsigned short f2bf(float f) {
  unsigned u = __float_as_uint(f);
  u = (u + 0x7FFFu + ((u >> 16) & 1u)) >> 16;
  return (unsigned short)u;
}

// ---- W -> sign(W) as bf16 bits, plus per-block partial sums of |W| ------
__global__ __launch_bounds__(256) void wsign_kernel(
    const float* __restrict__ W, unsigned short* __restrict__ S,
    float* __restrict__ partials) {
  const int tid = threadIdx.x;
  const int stride = gridDim.x * 256;
  const int total4 = (4096 * 4096) / 4;
  float s = 0.f;
  for (int i = blockIdx.x * 256 + tid; i < total4; i += stride) {
    float4 w = reinterpret_cast<const float4*>(W)[i];
    ushort4 o;
    o.x = w.x > 0.f ? 0x3F80 : (w.x < 0.f ? 0xBF80 : 0);
    o.y = w.y > 0.f ? 0x3F80 : (w.y < 0.f ? 0xBF80 : 0);
    o.z = w.z > 0.f ? 0x3F80 : (w.z < 0.f ? 0xBF80 : 0);
    o.w = w.w > 0.f ? 0x3F80 : (w.w < 0.f ? 0xBF80 : 0);
    reinterpret_cast<ushort4*>(S)[i] = o;
    s += fabsf(w.x) + fabsf(w.y) + fabsf(w.z) + fabsf(w.w);
  }
#pragma unroll
  for (int off = 32; off > 0; off >>= 1) s += __shfl_down(s, off, 64);
  __shared__ float sm[4];
  if ((tid & 63) == 0) sm[tid >> 6] = s;
  __syncthreads();
  if (tid == 0) partials[blockIdx.x] = sm[0] + sm[1] + sm[2] + sm[3];
}

// ---- x f32 -> bf16 ------------------------------------------------------
__global__ __launch_bounds__(256) void xconv_kernel(
    const float* __restrict__ X, unsigned short* __restrict__ XB) {
  const int total4 = (8192 * 4096) / 4;
  const int stride = gridDim.x * 256;
  for (int i = blockIdx.x * 256 + threadIdx.x; i < total4; i += stride) {
    float4 v = reinterpret_cast<const float4*>(X)[i];
    ushort4 o;
    o.x = f2bf(v.x);
    o.y = f2bf(v.y);
    o.z = f2bf(v.z);
    o.w = f2bf(v.w);
    reinterpret_cast<ushort4*>(XB)[i] = o;
  }
}

// ---- deterministic reduce of partials -> scale = mean(|W|) --------------
__global__ __launch_bounds__(256) void finalize_kernel(
    const float* __restrict__ partials, float* __restrict__ scale) {
  const int tid = threadIdx.x;
  float s = 0.f;
  for (int i = tid; i < 2048; i += 256) s += partials[i];
#pragma unroll
  for (int off = 32; off > 0; off >>= 1) s += __shfl_down(s, off, 64);
  __shared__ float sm[4];
  if ((tid & 63) == 0) sm[tid >> 6] = s;
  __syncthreads();
  if (tid == 0) scale[0] = (sm[0] + sm[1] + sm[2] + sm[3]) * (1.0f / 16777216.0f);
}

// ---- 256x256x64 8-wave 8-phase bf16 GEMM (m201 template port) -----------
// Iteration covers steps t0=2i (parity0 slots) and t0+1 (parity1).
// Per phase: {4-or-12 ds_read; 1 half-tile stage; [lgkm8]; [vmcnt gate];
//             barrier; lgkm0; setprio+16 MFMA; barrier}.
// Stage map: P0:A0(t0+1)s2 P1:A1(t0+1)s3 P2:B0(t0+2)s4 P3:B1(t0+2)s5
//            P4:A0(t0+2)s0 P5:A1(t0+2)s1 P6:B0(t0+3)s6 P7:B1(t0+3)s7
// Gates: vmcnt(4) at P3 (step t0+1 resident) and P7 (step t0+2 resident);
// last iter: P3 -> vmcnt(0), P7 gate dropped. FIFO-audited.
__global__ __launch_bounds__(512, 2) void gemm_sign_kernel(
    const unsigned short* __restrict__ A,  // [8192][4096] bf16 bits
    const unsigned short* __restrict__ B,  // [4096][4096] bf16 sign
    const float* __restrict__ scale_p, float* __restrict__ C) {
  constexpr int M = 8192, N = 4096, K = 4096;
  constexpr int NT = K / 64;   // 64 K-steps
  constexpr int NI = NT / 2;   // 32 iterations
  __shared__ __align__(16) unsigned short lds[65536];  // 128 KiB

  const int tid = threadIdx.x;
  const int wid = tid >> 6;
  const int lane = tid & 63;
  const int wr = wid >> 2;           // 0..1 : A half (M-rows)
  const int wc = wid & 3;            // 0..3 : 64-col group
  const int bh = wc >> 1;            // B half slot
  const int bsub = (wc & 1) * 4096;  // 64-row band within B half
  const int fr = lane & 15;
  const int fq = lane >> 4;
  const int s0 = (fq ^ (fr & 7)) * 8;  // swizzled k-slot; kk=1 at s0^32

  // XCD-aware swizzle; nwg = 512, divisible by 8
  const int bid = blockIdx.x;
  const int swz = (bid & 7) * 64 + (bid >> 3);
  const int tm = swz >> 4, tn = swz & 15;

  // staging sources (per-thread, pre-inverse-swizzled)
  const int srow = tid >> 3;
  const int sg = (tid & 7) ^ (srow & 7);
  const unsigned short* aSrc0 = A + (size_t)(tm * 256 + srow) * K + sg * 8;
  const unsigned short* aSrc1 = aSrc0 + (size_t)128 * K;
  const unsigned short* bSrc0 = B + (size_t)(tn * 256 + srow) * K + sg * 8;
  const unsigned short* bSrc1 = bSrc0 + (size_t)128 * K;

#define STAGE(srcBase, slotIdx, koff)                              \
  do {                                                             \
    const unsigned short* _s = (srcBase) + (koff);                 \
    unsigned short* _d = &lds[(slotIdx) * 8192 + wid * 512];       \
    GLOAD(_s, _d);                                                 \
    GLOAD(_s + (size_t)64 * K, _d + 4096);                         \
  } while (0)

  // fragment read bases (loop-invariant)
  const unsigned short* aSp0 = lds + (0 + wr) * 8192 + fr * 64;       // parity0 A
  const unsigned short* aSp1 = lds + (2 + wr) * 8192 + fr * 64;       // parity1 A
  const unsigned short* bSp0 = lds + (4 + bh) * 8192 + bsub + fr * 64;  // parity0 B
  const unsigned short* bSp1 = lds + (6 + bh) * 8192 + bsub + fr * 64;  // parity1 B

  f32x4 acc[8][4];
#pragma unroll
  for (int m = 0; m < 8; ++m)
#pragma unroll
    for (int n = 0; n < 4; ++n) acc[m][n] = (f32x4){0.f, 0.f, 0.f, 0.f};

#define RD_B(bS)                                                       \
  _Pragma("unroll") for (int n = 0; n < 4; ++n) {                      \
    bq[n][0] = *(const bf16x8*)((bS) + n * 1024 + s0);                 \
    bq[n][1] = *(const bf16x8*)((bS) + n * 1024 + (s0 ^ 32));          \
  }
#define RD_A(aS, q)                                                    \
  _Pragma("unroll") for (int m2 = 0; m2 < 2; ++m2) {                   \
    av[m2][0] = *(const bf16x8*)((aS) + (2 * (q) + m2) * 1024 + s0);   \
    av[m2][1] = *(const bf16x8*)((aS) + (2 * (q) + m2) * 1024 + (s0 ^ 32)); \
  }
#define QMFMA(q)                                                       \
  do {                                                                 \
    __builtin_amdgcn_s_setprio(1);                                     \
    _Pragma("unroll") for (int m2 = 0; m2 < 2; ++m2)                   \
        _Pragma("unroll") for (int n = 0; n < 4; ++n) {                \
      acc[2 * (q) + m2][n] =                                           \
          MFMA(av[m2][0], bq[n][0], acc[2 * (q) + m2][n], 0, 0, 0);    \
      acc[2 * (q) + m2][n] =                                           \
          MFMA(av[m2][1], bq[n][1], acc[2 * (q) + m2][n], 0, 0, 0);    \
    }                                                                  \
    __builtin_amdgcn_s_setprio(0);                                     \
  } while (0)

  // Prologue: 6 half-tiles in steady-state FIFO order
  STAGE(bSrc0, 4, 0);    // B0(0)
  STAGE(bSrc1, 5, 0);    // B1(0)
  STAGE(aSrc0, 0, 0);    // A0(0)
  STAGE(aSrc1, 1, 0);    // A1(0)
  STAGE(bSrc0, 6, 64);   // B0(1)
  STAGE(bSrc1, 7, 64);   // B1(1)
  asm volatile("s_waitcnt vmcnt(4)" ::: "memory");  // step 0 resident
  BARRIER();

  for (int i = 0; i < NI; ++i) {
    const int t0 = 2 * i;
    const int k1 = (t0 + 1) * 64, k2 = (t0 + 2) * 64, k3 = (t0 + 3) * 64;
    bf16x8 bq[4][2], av[2][2];

    // ---- P0: B(t0) + A q0; stage A0(t0+1) ----
    RD_B(bSp0);
    RD_A(aSp0, 0);
    STAGE(aSrc0, 2, k1);          // t0+1 < NT always (t0 <= NT-2)
    LGKM8;
    BARRIER(); LGKM0; QMFMA(0); BARRIER();

    // ---- P1: A q1; stage A1(t0+1) ----
    RD_A(aSp0, 1);
    STAGE(aSrc1, 3, k1);
    BARRIER(); LGKM0; QMFMA(1); BARRIER();

    // ---- P2: A q2; stage B0(t0+2) ----
    RD_A(aSp0, 2);
    if (t0 + 2 < NT) STAGE(bSrc0, 4, k2);
    BARRIER(); LGKM0; QMFMA(2); BARRIER();

    // ---- P3: A q3; stage B1(t0+2); GATE step t0+1 ----
    RD_A(aSp0, 3);
    if (t0 + 2 < NT) {
      STAGE(bSrc1, 5, k2);
      asm volatile("s_waitcnt vmcnt(4)" ::: "memory");
    } else {
      asm volatile("s_waitcnt vmcnt(0)" ::: "memory");
    }
    BARRIER(); LGKM0; QMFMA(3); BARRIER();

    // ---- P4: B(t0+1) + A q0; stage A0(t0+2) ----
    RD_B(bSp1);
    RD_A(aSp1, 0);
    if (t0 + 2 < NT) STAGE(aSrc0, 0, k2);
    LGKM8;
    BARRIER(); LGKM0; QMFMA(0); BARRIER();

    // ---- P5: A q1; stage A1(t0+2) ----
    RD_A(aSp1, 1);
    if (t0 + 2 < NT) STAGE(aSrc1, 1, k2);
    BARRIER(); LGKM0; QMFMA(1); BARRIER();

    // ---- P6: A q2; stage B0(t0+3) ----
    RD_A(aSp1, 2);
    if (t0 + 3 < NT) STAGE(bSrc0, 6, k3);
    BARRIER(); LGKM0; QMFMA(2); BARRIER();

    // ---- P7: A q3; stage B1(t0+3); GATE step t0+2 ----
    RD_A(aSp1, 3);
    if (t0 + 3 < NT) {
      STAGE(bSrc1, 7, k3);
      asm volatile("s_waitcnt vmcnt(4)" ::: "memory");
    }
    BARRIER(); LGKM0; QMFMA(3); BARRIER();
  }

  // ---- epilogue ----
  const float sc = *scale_p;
  const int crow0 = tm * 256 + wr * 128 + fq * 4;
  const int ccol0 = tn * 256 + wc * 64 + fr;
#pragma unroll
  for (int m = 0; m < 8; ++m) {
#pragma unroll
    for (int n = 0; n < 4; ++n) {
      f32x4 v = acc[m][n];
      float* cp = C + (size_t)(crow0 + m * 16) * N + ccol0 + n * 16;
#pragma unroll
      for (int j = 0; j < 4; ++j) cp[(size_t)j * N] = v[j] * sc;
    }
  }
#undef STAGE
#undef RD_A
#undef RD_B
#undef QMFMA
}

extern "C" void kernel_launch(void* const* d_in, const int* in_sizes, int n_in,
                              void* d_out, int out_size, void* d_ws,
                              size_t ws_size, hipStream_t stream) {
  const float* x = (const float*)d_in[0];   // [8192][4096] f32
  const float* w = (const float*)d_in[1];   // [4096][4096] f32
  float* out = (float*)d_out;               // [8192][4096] f32

  char* ws = (char*)d_ws;
  unsigned short* xb = (unsigned short*)ws;                   // 64 MiB
  unsigned short* sb = (unsigned short*)(ws + 67108864);      // 32 MiB
  float* partials = (float*)(ws + 100663296);                 // 2048 f32
  float* scale = (float*)(ws + 100663296 + 8192);             // 1 f32

  wsign_kernel<<<2048, 256, 0, stream>>>(w, sb, partials);
  xconv_kernel<<<2048, 256, 0, stream>>>(x, xb);
  finalize_kernel<<<1, 256, 0, stream>>>(partials, scale);
  gemm_sign_kernel<<<512, 512, 0, stream>>>(xb, sb, scale, out);
}

// Round 7
// 177.806 us; speedup vs baseline: 1.6860x; 1.4875x over previous
//
#include <hip/hip_runtime.h>
#include <hip/hip_bf16.h>
#include <stdint.h>

typedef __attribute__((ext_vector_type(4))) int i32x4;

#define GLOAD(g, l) __builtin_amdgcn_global_load_lds(                      \
    (const __attribute__((address_space(1))) void*)(g),                    \
    (__attribute__((address_space(3))) void*)(l), 16, 0, 0)

#define MFMAI8 __builtin_amdgcn_mfma_i32_16x16x64_i8
#define BARRIER __builtin_amdgcn_s_barrier
#define LGKM0 asm volatile("s_waitcnt lgkmcnt(0)" ::: "memory")
#define LGKM8 asm volatile("s_waitcnt lgkmcnt(8)" ::: "memory")

// ---- W -> sign(W) as i8 {-1,0,1}, plus per-block partial sums of |W| ----
__global__ __launch_bounds__(256) void wsign_kernel(
    const float* __restrict__ W, char* __restrict__ S,
    float* __restrict__ partials) {
  const int tid = threadIdx.x;
  const int idx = blockIdx.x * 256 + tid;  // one int4 (16 f32 -> 16 i8) each
  const float4* wp = reinterpret_cast<const float4*>(W) + (size_t)idx * 4;
  float s = 0.f;
  int out[4];
#pragma unroll
  for (int i = 0; i < 4; ++i) {
    float4 w = wp[i];
    int b0 = (w.x > 0.f) - (w.x < 0.f);
    int b1 = (w.y > 0.f) - (w.y < 0.f);
    int b2 = (w.z > 0.f) - (w.z < 0.f);
    int b3 = (w.w > 0.f) - (w.w < 0.f);
    out[i] = (b0 & 255) | ((b1 & 255) << 8) | ((b2 & 255) << 16) |
             ((b3 & 255) << 24);
    s += fabsf(w.x) + fabsf(w.y) + fabsf(w.z) + fabsf(w.w);
  }
  reinterpret_cast<int4*>(S)[idx] =
      make_int4(out[0], out[1], out[2], out[3]);
#pragma unroll
  for (int off = 32; off > 0; off >>= 1) s += __shfl_down(s, off, 64);
  __shared__ float sm[4];
  if ((tid & 63) == 0) sm[tid >> 6] = s;
  __syncthreads();
  if (tid == 0) partials[blockIdx.x] = sm[0] + sm[1] + sm[2] + sm[3];
}

// ---- x f32 -> i8 per-row quantization; qrow = amax/127 ------------------
__global__ __launch_bounds__(256) void xquant_kernel(
    const float* __restrict__ X, char* __restrict__ XQ,
    float* __restrict__ qrow) {
  const int row = blockIdx.x;
  const int tid = threadIdx.x;
  const float4* xr = reinterpret_cast<const float4*>(X + (size_t)row * 4096);
  float4 v[4];
  float am = 0.f;
#pragma unroll
  for (int i = 0; i < 4; ++i) {
    v[i] = xr[tid * 4 + i];
    am = fmaxf(am, fmaxf(fmaxf(fabsf(v[i].x), fabsf(v[i].y)),
                         fmaxf(fabsf(v[i].z), fabsf(v[i].w))));
  }
#pragma unroll
  for (int off = 1; off < 64; off <<= 1)
    am = fmaxf(am, __shfl_xor(am, off, 64));
  __shared__ float wm[4];
  if ((tid & 63) == 0) wm[tid >> 6] = am;
  __syncthreads();
  float amax = fmaxf(fmaxf(wm[0], wm[1]), fmaxf(wm[2], wm[3]));
  amax = fmaxf(amax, 1e-20f);
  const float rq = 127.f / amax;
  int out[4];
#pragma unroll
  for (int i = 0; i < 4; ++i) {
    int b0 = __float2int_rn(v[i].x * rq);
    int b1 = __float2int_rn(v[i].y * rq);
    int b2 = __float2int_rn(v[i].z * rq);
    int b3 = __float2int_rn(v[i].w * rq);
    out[i] = (b0 & 255) | ((b1 & 255) << 8) | ((b2 & 255) << 16) |
             ((b3 & 255) << 24);
  }
  reinterpret_cast<int4*>(XQ + (size_t)row * 4096)[tid] =
      make_int4(out[0], out[1], out[2], out[3]);
  if (tid == 0) qrow[row] = amax * (1.f / 127.f);
}

// ---- deterministic reduce of partials -> scale = mean(|W|) --------------
__global__ __launch_bounds__(256) void finalize_kernel(
    const float* __restrict__ partials, float* __restrict__ scale) {
  const int tid = threadIdx.x;
  float s = 0.f;
  for (int i = tid; i < 4096; i += 256) s += partials[i];
#pragma unroll
  for (int off = 32; off > 0; off >>= 1) s += __shfl_down(s, off, 64);
  __shared__ float sm[4];
  if ((tid & 63) == 0) sm[tid >> 6] = s;
  __syncthreads();
  if (tid == 0) scale[0] = (sm[0] + sm[1] + sm[2] + sm[3]) * (1.0f / 16777216.0f);
}

// ---- 256x256x128 8-wave 8-phase i8 GEMM (round-6 schedule, i8 dtype) ----
// Byte-isomorphic to the bf16 kernel: rows 128 B, 16 KiB slots, same
// 0-conflict XOR swizzle, same vmcnt(4)/lgkm gates. NT=32 K-steps.
// C[r][c] = scale_w * qrow[r] * sum_k xq[r][k]*sgn[c][k]
__global__ __launch_bounds__(512, 2) void gemm_i8_kernel(
    const char* __restrict__ A,  // [8192][4096] i8
    const char* __restrict__ B,  // [4096][4096] i8 sign
    const float* __restrict__ scale_p, const float* __restrict__ qrow,
    float* __restrict__ C) {
  constexpr int M = 8192, N = 4096, K = 4096;
  constexpr int NT = K / 128;  // 32 K-steps
  constexpr int NI = NT / 2;   // 16 iterations
  __shared__ __align__(16) char lds[131072];  // 8 slots x 16 KiB

  const int tid = threadIdx.x;
  const int wid = tid >> 6;
  const int lane = tid & 63;
  const int wr = wid >> 2;            // 0..1 : A half (M-rows)
  const int wc = wid & 3;             // 0..3 : 64-col group
  const int bh = wc >> 1;             // B half slot
  const int bsub = (wc & 1) * 8192;   // 64-row band within B half (bytes)
  const int fr = lane & 15;
  const int fq = lane >> 4;
  // swizzled 16B-slot byte offsets, kk = 0,1 (k = kk*64 + fq*16 + j)
  const int sk0 = ((fq) ^ (fr & 7)) * 16;
  const int sk1 = ((4 + fq) ^ (fr & 7)) * 16;

  // XCD-aware swizzle; nwg = 512, divisible by 8
  const int bid = blockIdx.x;
  const int swz = (bid & 7) * 64 + (bid >> 3);
  const int tm = swz >> 4, tn = swz & 15;

  // staging sources (per-thread, pre-inverse-swizzled); 16B granules
  const int srow = tid >> 3;
  const int sg = (tid & 7) ^ (srow & 7);
  const char* aSrc0 = A + (size_t)(tm * 256 + srow) * K + sg * 16;
  const char* aSrc1 = aSrc0 + (size_t)128 * K;
  const char* bSrc0 = B + (size_t)(tn * 256 + srow) * K + sg * 16;
  const char* bSrc1 = bSrc0 + (size_t)128 * K;

#define STAGE(srcBase, slotIdx, koff)                              \
  do {                                                             \
    const char* _s = (srcBase) + (koff);                           \
    char* _d = lds + (slotIdx) * 16384 + wid * 1024;               \
    GLOAD(_s, _d);                                                 \
    GLOAD(_s + (size_t)64 * K, _d + 8192);                         \
  } while (0)

  // fragment read bases (loop-invariant)
  const char* aSp0 = lds + (0 + wr) * 16384 + fr * 128;
  const char* aSp1 = lds + (2 + wr) * 16384 + fr * 128;
  const char* bSp0 = lds + (4 + bh) * 16384 + bsub + fr * 128;
  const char* bSp1 = lds + (6 + bh) * 16384 + bsub + fr * 128;

  i32x4 acc[8][4];
#pragma unroll
  for (int m = 0; m < 8; ++m)
#pragma unroll
    for (int n = 0; n < 4; ++n) acc[m][n] = (i32x4){0, 0, 0, 0};

#define RD_B(bS)                                                       \
  _Pragma("unroll") for (int n = 0; n < 4; ++n) {                      \
    bq[n][0] = *(const i32x4*)((bS) + n * 2048 + sk0);                 \
    bq[n][1] = *(const i32x4*)((bS) + n * 2048 + sk1);                 \
  }
#define RD_A(aS, q)                                                    \
  _Pragma("unroll") for (int m2 = 0; m2 < 2; ++m2) {                   \
    av[m2][0] = *(const i32x4*)((aS) + (2 * (q) + m2) * 2048 + sk0);   \
    av[m2][1] = *(const i32x4*)((aS) + (2 * (q) + m2) * 2048 + sk1);   \
  }
#define QMFMA(q)                                                       \
  do {                                                                 \
    __builtin_amdgcn_s_setprio(1);                                     \
    _Pragma("unroll") for (int m2 = 0; m2 < 2; ++m2)                   \
        _Pragma("unroll") for (int n = 0; n < 4; ++n) {                \
      acc[2 * (q) + m2][n] =                                           \
          MFMAI8(av[m2][0], bq[n][0], acc[2 * (q) + m2][n], 0, 0, 0);  \
      acc[2 * (q) + m2][n] =                                           \
          MFMAI8(av[m2][1], bq[n][1], acc[2 * (q) + m2][n], 0, 0, 0);  \
    }                                                                  \
    __builtin_amdgcn_s_setprio(0);                                     \
  } while (0)

  // Prologue: 6 half-tiles in steady-state FIFO order (koff in bytes)
  STAGE(bSrc0, 4, 0);     // B0(0)
  STAGE(bSrc1, 5, 0);     // B1(0)
  STAGE(aSrc0, 0, 0);     // A0(0)
  STAGE(aSrc1, 1, 0);     // A1(0)
  STAGE(bSrc0, 6, 128);   // B0(1)
  STAGE(bSrc1, 7, 128);   // B1(1)
  asm volatile("s_waitcnt vmcnt(4)" ::: "memory");  // step 0 resident
  BARRIER();

  for (int i = 0; i < NI; ++i) {
    const int t0 = 2 * i;
    const int k1 = (t0 + 1) * 128, k2 = (t0 + 2) * 128, k3 = (t0 + 3) * 128;
    i32x4 bq[4][2], av[2][2];

    // ---- P0: B(t0) + A q0; stage A0(t0+1) ----
    RD_B(bSp0);
    RD_A(aSp0, 0);
    STAGE(aSrc0, 2, k1);
    LGKM8;
    BARRIER(); LGKM0; QMFMA(0); BARRIER();

    // ---- P1: A q1; stage A1(t0+1) ----
    RD_A(aSp0, 1);
    STAGE(aSrc1, 3, k1);
    BARRIER(); LGKM0; QMFMA(1); BARRIER();

    // ---- P2: A q2; stage B0(t0+2) ----
    RD_A(aSp0, 2);
    if (t0 + 2 < NT) STAGE(bSrc0, 4, k2);
    BARRIER(); LGKM0; QMFMA(2); BARRIER();

    // ---- P3: A q3; stage B1(t0+2); GATE step t0+1 ----
    RD_A(aSp0, 3);
    if (t0 + 2 < NT) {
      STAGE(bSrc1, 5, k2);
      asm volatile("s_waitcnt vmcnt(4)" ::: "memory");
    } else {
      asm volatile("s_waitcnt vmcnt(0)" ::: "memory");
    }
    BARRIER(); LGKM0; QMFMA(3); BARRIER();

    // ---- P4: B(t0+1) + A q0; stage A0(t0+2) ----
    RD_B(bSp1);
    RD_A(aSp1, 0);
    if (t0 + 2 < NT) STAGE(aSrc0, 0, k2);
    LGKM8;
    BARRIER(); LGKM0; QMFMA(0); BARRIER();

    // ---- P5: A q1; stage A1(t0+2) ----
    RD_A(aSp1, 1);
    if (t0 + 2 < NT) STAGE(aSrc1, 1, k2);
    BARRIER(); LGKM0; QMFMA(1); BARRIER();

    // ---- P6: A q2; stage B0(t0+3) ----
    RD_A(aSp1, 2);
    if (t0 + 3 < NT) STAGE(bSrc0, 6, k3);
    BARRIER(); LGKM0; QMFMA(2); BARRIER();

    // ---- P7: A q3; stage B1(t0+3); GATE step t0+2 ----
    RD_A(aSp1, 3);
    if (t0 + 3 < NT) {
      STAGE(bSrc1, 7, k3);
      asm volatile("s_waitcnt vmcnt(4)" ::: "memory");
    }
    BARRIER(); LGKM0; QMFMA(3); BARRIER();
  }

  // ---- epilogue: C = scale_w * qrow[row] * acc ----
  const float sc = *scale_p;
  const int crow0 = tm * 256 + wr * 128 + fq * 4;
  const int ccol0 = tn * 256 + wc * 64 + fr;
#pragma unroll
  for (int m = 0; m < 8; ++m) {
    const int row = crow0 + m * 16;
    float q[4];
#pragma unroll
    for (int j = 0; j < 4; ++j) q[j] = sc * qrow[row + j];
#pragma unroll
    for (int n = 0; n < 4; ++n) {
      i32x4 v = acc[m][n];
      float* cp = C + (size_t)row * N + ccol0 + n * 16;
#pragma unroll
      for (int j = 0; j < 4; ++j) cp[(size_t)j * N] = (float)v[j] * q[j];
    }
  }
#undef STAGE
#undef RD_A
#undef RD_B
#undef QMFMA
}

extern "C" void kernel_launch(void* const* d_in, const int* in_sizes, int n_in,
                              void* d_out, int out_size, void* d_ws,
                              size_t ws_size, hipStream_t stream) {
  const float* x = (const float*)d_in[0];   // [8192][4096] f32
  const float* w = (const float*)d_in[1];   // [4096][4096] f32
  float* out = (float*)d_out;               // [8192][4096] f32

  char* ws = (char*)d_ws;
  char* xq = ws;                                   // 32 MiB
  char* sq = ws + 33554432;                        // 16 MiB
  float* qrow = (float*)(ws + 50331648);           // 8192 f32
  float* partials = (float*)(ws + 50331648 + 32768);  // 4096 f32
  float* scale = (float*)(ws + 50331648 + 32768 + 16384);

  wsign_kernel<<<4096, 256, 0, stream>>>(w, sq, partials);
  xquant_kernel<<<8192, 256, 0, stream>>>(x, xq, qrow);
  finalize_kernel<<<1, 256, 0, stream>>>(partials, scale);
  gemm_i8_kernel<<<512, 512, 0, stream>>>(xq, sq, scale, qrow, out);
}